// Round 8
// baseline (74.110 us; speedup 1.0000x reference)
//
#include <hip/hip_runtime.h>
#include <hip/hip_bf16.h>

// GCN forward, FUSED v3b: out = PReLU(adj @ (seq @ W^T) + bias)
// B=256, N=512, IN_FT=OUT_FT=64. Output fp32.
// grid = 512 (256 batches x 2 halves), block = 256 (4 waves), LDS 64 KB
// -> TWO independent blocks per CU so barrier/vmcnt stalls of one block
//    overlap the other block's HBM streaming.
// R7 bug fixed: depth-1 prefetch only (2 buffers can't hold 2 prefetched
// chunks); prologue stages chunk 0, loop stages it+1.

#define BATCH 256
#define NTOK  512
#define INF   64
#define OUTF  64

typedef __attribute__((ext_vector_type(8))) __bf16 bf16x8;
typedef __attribute__((ext_vector_type(4))) __bf16 bf16x4;
typedef __attribute__((ext_vector_type(4))) float  f32x4;

typedef const __attribute__((address_space(1))) char GChar;
typedef __attribute__((address_space(3))) char LChar;

__device__ __forceinline__ bf16x8 load_cvt8(const float* __restrict__ p) {
    float4 lo = *(const float4*)p;
    float4 hi = *(const float4*)(p + 4);
    bf16x8 r;
    r[0] = (__bf16)lo.x; r[1] = (__bf16)lo.y; r[2] = (__bf16)lo.z; r[3] = (__bf16)lo.w;
    r[4] = (__bf16)hi.x; r[5] = (__bf16)hi.y; r[6] = (__bf16)hi.z; r[7] = (__bf16)hi.w;
    return r;
}

__device__ __forceinline__ bf16x8 pack8(float4 lo, float4 hi) {
    bf16x8 r;
    r[0] = (__bf16)lo.x; r[1] = (__bf16)lo.y; r[2] = (__bf16)lo.z; r[3] = (__bf16)lo.w;
    r[4] = (__bf16)hi.x; r[5] = (__bf16)hi.y; r[6] = (__bf16)hi.z; r[7] = (__bf16)hi.w;
    return r;
}

__global__ __launch_bounds__(256, 2) void GCN_fused_kernel(
        const float* __restrict__ seq, const float* __restrict__ adj,
        const float* __restrict__ W, const float* __restrict__ bias,
        const float* __restrict__ alpha_p, float* __restrict__ out) {
    __shared__ float smem[16384];            // 64 KB per block (2 blocks/CU)

    // XCD-paired decode: p = (b&7) + 8*((b>>3)*2 + h)  (assumes XCD = p%8)
    int p  = blockIdx.x;
    int x  = p & 7;
    int q  = p >> 3;                         // (b>>3)*2 + h
    int b  = (q >> 1) * 8 + x;
    int h  = q & 1;
    int r0 = h * 256;                        // this block's adj row base

    int tid  = threadIdx.x;
    int wave = tid >> 6;                     // 0..3 = col-group
    int lane = tid & 63;
    int row16 = lane & 15;
    int g     = lane >> 4;                   // 0..3
    int rs    = row16 & 7;

    __bf16* sft = (__bf16*)smem;             // [64 o][512 k] bf16, overlays both bufs
    float* buf0 = smem;                      // [16 rows x 512 k] fp32 = 32 KB
    float* buf1 = smem + 8192;

    const float* gadj = adj + (size_t)b * NTOK * NTOK;

    // STAGE one [16 x 512] chunk: 32 x global_load_lds (1 KB), 8 per wave.
    // idx = wave*8+i: row = idx>>1 (wave-uniform), half = idx&1; lane fetches
    // swizzled slot (lane ^ (row&7)) within the row's 1-KB half so linear LDS
    // holds LDS[row][s] = G[row][half*64 + (s ^ (row&7))].
#define STAGE(dstf, rbase) do {                                                \
    _Pragma("unroll")                                                          \
    for (int i_ = 0; i_ < 8; ++i_) {                                           \
        int idx_  = wave * 8 + i_;                                             \
        int row_  = idx_ >> 1;                                                 \
        int half_ = idx_ & 1;                                                  \
        __builtin_amdgcn_global_load_lds(                                      \
            (GChar*)(gadj + (size_t)((rbase) + row_) * NTOK + half_ * 256      \
                     + (lane ^ (row_ & 7)) * 4),                               \
            (LChar*)((dstf) + idx_ * 256), 16, 0, 0);                          \
    }                                                                          \
} while (0)

    // ================= Phase 1: sft[o][k] = (seq @ W^T)^T ===================
    // Wave handles tokens [wave*128, wave*128+128), all 64 o.
    {
        int mb = wave * 128;
        bf16x8 wf[4][2];
#pragma unroll
        for (int nt = 0; nt < 4; ++nt)
#pragma unroll
            for (int ks = 0; ks < 2; ++ks)
                wf[nt][ks] = load_cvt8(W + (size_t)(nt * 16 + row16) * INF + ks * 32 + g * 8);

#pragma unroll
        for (int mt2 = 0; mt2 < 8; ++mt2) {
            f32x4 pa[4] = {};
#pragma unroll
            for (int ks = 0; ks < 2; ++ks) {
                bf16x8 af = load_cvt8(seq + ((size_t)b * NTOK + mb + mt2 * 16 + row16) * INF + ks * 32 + g * 8);
#pragma unroll
                for (int nt = 0; nt < 4; ++nt)
                    pa[nt] = __builtin_amdgcn_mfma_f32_16x16x32_bf16(af, wf[nt][ks], pa[nt], 0, 0, 0);
            }
            // D: col(o)=row16-part, row(tok)=g*4+reg. Swizzled store:
            // 16-B slot s = k>>3 stored at s ^ (o&7), within-slot offset k&7.
#pragma unroll
            for (int nt = 0; nt < 4; ++nt) {
                int o    = nt * 16 + row16;
                int ktok = mb + mt2 * 16 + g * 4;
                int sw   = (ktok >> 3) ^ (o & 7);
                bf16x4 v;
                v[0] = (__bf16)pa[nt][0]; v[1] = (__bf16)pa[nt][1];
                v[2] = (__bf16)pa[nt][2]; v[3] = (__bf16)pa[nt][3];
                *(bf16x4*)((char*)sft + (size_t)o * 1024 + sw * 16 + (ktok & 7) * 2) = v;
            }
        }
    }
    int orow     = wave * 16 + row16;
    float bv     = bias[orow];
    float alphav = alpha_p[0];
    __syncthreads();

    // ============ Redistribute: B-frags, this wave's 16 cols, all K =========
    bf16x8 bbr[16];
#pragma unroll
    for (int t = 0; t < 16; ++t) {
        int sw = ((t << 2) + g) ^ rs;
        bbr[t] = *(const bf16x8*)((const char*)sft + (size_t)orow * 1024 + sw * 16);
    }
    __syncthreads();                         // all bbr reads done; sft LDS is dead

    // ================= Phase 2: 16 chunks of [16 rows x 512 k] ==============
    STAGE(buf0, r0);                         // depth-1 prologue: chunk 0 only

#pragma unroll 1
    for (int it = 0; it < 16; ++it) {
        float* cur = (it & 1) ? buf1 : buf0;
        float* nxt = (it & 1) ? buf0 : buf1;

        if (it > 0) {                        // all waves done reading nxt's old chunk
            __builtin_amdgcn_sched_barrier(0);
            __builtin_amdgcn_s_barrier();
            __builtin_amdgcn_sched_barrier(0);
        }
        if (it < 15) STAGE(nxt, r0 + (it + 1) * 16);
        __builtin_amdgcn_sched_barrier(0);
        // per-wave outstanding before the wait (oldest -> newest):
        //   it==0:        [cur 8][next 8]                       -> wait 8
        //   1<=it<=14:    [stores 4][cur 8][stores 4][next 8]   -> wait 12
        //   it==15:       [stores 4][cur 8][stores 4]           -> wait 4
        if (it == 0)      asm volatile("s_waitcnt vmcnt(8)"  ::: "memory");
        else if (it < 15) asm volatile("s_waitcnt vmcnt(12)" ::: "memory");
        else              asm volatile("s_waitcnt vmcnt(4)"  ::: "memory");
        __builtin_amdgcn_sched_barrier(0);
        __builtin_amdgcn_s_barrier();        // chunk landed for ALL staging waves
        __builtin_amdgcn_sched_barrier(0);

        // compute: 16 chunk-rows x this wave's 16 cols, full K=512. 16 MFMAs.
        f32x4 acc;
        acc[0] = bv; acc[1] = bv; acc[2] = bv; acc[3] = bv;
        int rowb = row16 * 512;              // lane's A-row (2 KB) in the chunk
#pragma unroll
        for (int ks = 0; ks < 16; ++ks) {
            int s0 = (ks * 8 + g * 2) ^ rs;  // even base -> partner slot is ^1
            float4 f0 = *(const float4*)(cur + rowb + s0 * 4);
            float4 f1 = *(const float4*)(cur + rowb + (s0 ^ 1) * 4);
            bf16x8 a = pack8(f0, f1);
            acc = __builtin_amdgcn_mfma_f32_16x16x32_bf16(a, bbr[ks], acc, 0, 0, 0);
        }

        // epilogue: PReLU + store (bias pre-loaded in acc); C/D row = g*4+j
        int m = r0 + it * 16 + g * 4;
        float* op = out + ((size_t)b * NTOK + m) * OUTF + orow;
#pragma unroll
        for (int j = 0; j < 4; ++j) {
            float v = acc[j];
            op[(size_t)j * OUTF] = (v >= 0.f) ? v : alphav * v;
        }
    }
#undef STAGE
}

extern "C" void kernel_launch(void* const* d_in, const int* in_sizes, int n_in,
                              void* d_out, int out_size, void* d_ws, size_t ws_size,
                              hipStream_t stream) {
    const float* seq   = (const float*)d_in[0];
    const float* adj   = (const float*)d_in[1];
    const float* W     = (const float*)d_in[2];
    const float* bias  = (const float*)d_in[3];
    const float* alpha = (const float*)d_in[4];
    float* out = (float*)d_out;

    GCN_fused_kernel<<<dim3(2 * BATCH), dim3(256), 0, stream>>>(seq, adj, W, bias, alpha, out);
}